// Round 3
// baseline (369.780 us; speedup 1.0000x reference)
//
#include <hip/hip_runtime.h>

// Max-unpooling (SegNet) scatter. B=32, H=W=64, C=128.
//   image_size = H*W*C        = 2^19  (per-batch pooled elements)
//   out_image  = 4*image_size = 2^21  (per-batch output elements)
//   logical output            = B * out_image = 2^26 floats = 2^24 float4s
// Output flat index = b*out_image + (am mod out_image).
//
// R5 change (theory: out_size is BYTES, not elements):
//  - The harness poison fill writes exactly 2^30 bytes -> the out allocation
//    is 1 GiB = 4x the logical 268 MB output -> out_size is a byte count.
//    Our zero_out (on4 = out_size>>2 = 67M float4s) was therefore zeroing
//    1 GiB, i.e. 4x the required traffic (~168 us), which is why R0->R2
//    kernel restructuring never moved dur_us (closure: 168 fill + 168 zero
//    + 33 scatter ~= 369).
//  - Fix: zero exactly 2^24 float4s (268 MB, the logical output). Both unit
//    interpretations of out_size agree on this count; shape is fixed by the
//    problem (shifts below are already hard-coded to it).
// Predicted: zero ~45 us @ ~6 TB/s (WRITE_SIZE 262,144 KB), scatter ~33 us,
// dur_us ~245-270 (remaining floor = the harness's own 1 GiB poison fill).

#define IMAGE_SHIFT 19
#define OUTIMG_SHIFT 21
#define OUTIMG_MASK ((1 << OUTIMG_SHIFT) - 1)
#define OUT_F4      (1 << 24)   // logical output float4 count (268 MB)
#define IN_F4       (1 << 22)   // pooled-input float4 count   (67 MB)

typedef float f32x4 __attribute__((ext_vector_type(4)));
typedef int   i32x4 __attribute__((ext_vector_type(4)));

__global__ __launch_bounds__(256) void zero_out(f32x4* __restrict__ out, int n4)
{
    const int stride = gridDim.x * blockDim.x;
    const f32x4 z = {0.f, 0.f, 0.f, 0.f};
    for (int t = blockIdx.x * blockDim.x + threadIdx.x; t < n4; t += stride) {
        __builtin_nontemporal_store(z, &out[t]);
    }
}

__global__ __launch_bounds__(256) void unpool_scatter(
    const f32x4* __restrict__ values,
    const i32x4* __restrict__ argmax,
    float*       __restrict__ out,
    int n4)
{
    const int stride = gridDim.x * blockDim.x;
    for (int t = blockIdx.x * blockDim.x + threadIdx.x; t < n4; t += stride) {
        f32x4 v = __builtin_nontemporal_load(&values[t]);
        i32x4 a = __builtin_nontemporal_load(&argmax[t]);

        int base_elem = t << 2;
        int b     = base_elem >> IMAGE_SHIFT;
        int obase = b << OUTIMG_SHIFT;

        int ix = a.x & OUTIMG_MASK;
        int iy = a.y & OUTIMG_MASK;
        int iz = a.z & OUTIMG_MASK;
        int iw = a.w & OUTIMG_MASK;

        // Fast path: 4 contiguous, 16B-aligned targets -> one float4 store.
        // (Holds when the 4 elements are consecutive channels of one output
        // position; degrades gracefully otherwise.)
        if (((ix & 3) == 0) && iy == ix + 1 && iz == ix + 2 && iw == ix + 3) {
            __builtin_nontemporal_store(v, (f32x4*)(out + obase + ix));
        } else {
            out[obase + ix] = v.x;
            out[obase + iy] = v.y;
            out[obase + iz] = v.z;
            out[obase + iw] = v.w;
        }
    }
}

extern "C" void kernel_launch(void* const* d_in, const int* in_sizes, int n_in,
                              void* d_out, int out_size, void* d_ws, size_t ws_size,
                              hipStream_t stream) {
    const float* values = (const float*)d_in[0];
    const int*   argmax = (const int*)d_in[1];
    float*       out    = (float*)d_out;

    // Shapes are fixed by the problem (see shifts above); do not trust the
    // units of out_size (byte count vs element count is ambiguous -- the 1 GiB
    // harness poison fill implies bytes). Zero exactly the logical output.
    const int on4 = OUT_F4;   // 16,777,216 float4s = 268 MB
    const int n4  = IN_F4;    // 4,194,304 float4 groups of pooled input

    const int block  = 256;
    const int blocks = 2048;  // 8 blocks/CU on 256 CUs; grid-stride the rest

    zero_out<<<blocks, block, 0, stream>>>((f32x4*)out, on4);

    unpool_scatter<<<blocks, block, 0, stream>>>(
        (const f32x4*)values, (const i32x4*)argmax, out, n4);
}

// Round 5
// 359.507 us; speedup vs baseline: 1.0286x; 1.0286x over previous
//
#include <hip/hip_runtime.h>

// Max-unpooling (SegNet) scatter. B=32, H=W=64, C=128.
//   image_size = H*W*C        = 2^19 elems/batch (2^17 float4 groups)
//   out_image  = 4*image_size = 2^21 elems/batch
//   output     = 2^26 floats  = 2^24 float4s (268 MB)
// Reference: out[b*2^21 + (am mod 2^21)] = v, with zeros elsewhere.
//
// R4 (fusion with verified disjoint ownership):
//  - Prior structure was zero(268 MB write) THEN scatter(128 MB read + 67 MB
//    write) = 463 MB in two dependent passes; dur_us stuck ~350-370 with the
//    harness 1 GiB poison fill (~165 us) inside the timed window.
//  - For this input, group t=(b,i) targets exactly quarter (b&3) of batch b:
//    p_k = ((b&3)<<19) + i + k. Each thread can therefore OWN the 4 output
//    slots {q*2^19 + i, q=0..3}: v to the argmax quarter, zeros to the other
//    three. Disjoint + covering -> no zero pass, one kernel, 396 MB total.
//  - Self-verifying: every thread checks its own 4 argmax values against the
//    pattern. All pass -> fused write provably correct. Any fail -> set ws
//    flag, write nothing; flag-guarded fallback kernels (full zero + general
//    scatter) redo everything. Fallbacks cost ~2 us each when dormant.
// Predicted: fused FETCH~131072 KB WRITE~262144 KB ~63-85 us; dur_us ~240-280.

#define IMAGE_SHIFT  19
#define OUTIMG_SHIFT 21
#define OUTIMG_MASK  ((1 << OUTIMG_SHIFT) - 1)
#define IN_F4        (1 << 22)   // pooled-input float4 groups
#define OUT_F4       (1 << 24)   // output float4 groups

typedef float f32x4 __attribute__((ext_vector_type(4)));
typedef int   i32x4 __attribute__((ext_vector_type(4)));

__global__ __launch_bounds__(64) void reset_flag(int* __restrict__ flag)
{
    if (threadIdx.x == 0) *flag = 0;
}

// One thread per input float4 group. Verifies its own argmax pattern, then
// writes its 4 owned output groups (one v, three zeros).
__global__ __launch_bounds__(256) void fused_unpool(
    const f32x4* __restrict__ values,
    const i32x4* __restrict__ argmax,
    f32x4*       __restrict__ out4,
    int*         __restrict__ flag)
{
    int t = blockIdx.x * blockDim.x + threadIdx.x;   // [0, 2^22)

    f32x4 v = values[t];
    i32x4 a = argmax[t];

    int b  = t >> 17;          // batch (2^17 groups per batch)
    int i4 = t & 131071;       // group index within batch
    int p0 = ((b & 3) << 19) | (i4 << 2);   // expected elem pos of .x in batch

    bool ok = ((a.x & OUTIMG_MASK) == p0)     &
              ((a.y & OUTIMG_MASK) == p0 + 1) &
              ((a.z & OUTIMG_MASK) == p0 + 2) &
              ((a.w & OUTIMG_MASK) == p0 + 3);

    if (ok) {
        const f32x4 z = {0.f, 0.f, 0.f, 0.f};
        int vq   = b & 3;
        int base = (b << 19) | i4;           // float4 index, quarter bits 17-18 clear
        out4[base            ] = (vq == 0) ? v : z;
        out4[base | (1 << 17)] = (vq == 1) ? v : z;
        out4[base | (2 << 17)] = (vq == 2) ? v : z;
        out4[base | (3 << 17)] = (vq == 3) ? v : z;
    } else {
        atomicOr(flag, 1);     // device-scope; fallbacks redo everything
    }
}

// ---- Fallback path (runs only if flag set; also used if no workspace) ----

__global__ __launch_bounds__(256) void zero_fallback(
    f32x4* __restrict__ out4, const int* __restrict__ flag, int n4)
{
    if (flag && *flag == 0) return;
    const int stride = gridDim.x * blockDim.x;
    const f32x4 z = {0.f, 0.f, 0.f, 0.f};
    for (int t = blockIdx.x * blockDim.x + threadIdx.x; t < n4; t += stride)
        out4[t] = z;
}

__global__ __launch_bounds__(256) void scatter_fallback(
    const f32x4* __restrict__ values,
    const i32x4* __restrict__ argmax,
    float*       __restrict__ out,
    const int*   __restrict__ flag, int n4)
{
    if (flag && *flag == 0) return;
    const int stride = gridDim.x * blockDim.x;
    for (int t = blockIdx.x * blockDim.x + threadIdx.x; t < n4; t += stride) {
        f32x4 v = values[t];
        i32x4 a = argmax[t];

        int base_elem = t << 2;
        int b     = base_elem >> IMAGE_SHIFT;
        int obase = b << OUTIMG_SHIFT;

        int ix = a.x & OUTIMG_MASK;
        int iy = a.y & OUTIMG_MASK;
        int iz = a.z & OUTIMG_MASK;
        int iw = a.w & OUTIMG_MASK;

        if (((ix & 3) == 0) && iy == ix + 1 && iz == ix + 2 && iw == ix + 3) {
            *(f32x4*)(out + obase + ix) = v;
        } else {
            out[obase + ix] = v.x;
            out[obase + iy] = v.y;
            out[obase + iz] = v.z;
            out[obase + iw] = v.w;
        }
    }
}

extern "C" void kernel_launch(void* const* d_in, const int* in_sizes, int n_in,
                              void* d_out, int out_size, void* d_ws, size_t ws_size,
                              hipStream_t stream) {
    const float* values = (const float*)d_in[0];
    const int*   argmax = (const int*)d_in[1];
    float*       out    = (float*)d_out;

    const int block = 256;

    if (d_ws && ws_size >= sizeof(int)) {
        int* flag = (int*)d_ws;
        reset_flag<<<1, 64, 0, stream>>>(flag);
        fused_unpool<<<IN_F4 / block, block, 0, stream>>>(
            (const f32x4*)values, (const i32x4*)argmax, (f32x4*)out, flag);
        // Dormant unless fused detected a pattern mismatch (~2 us each).
        zero_fallback<<<2048, block, 0, stream>>>((f32x4*)out, flag, OUT_F4);
        scatter_fallback<<<2048, block, 0, stream>>>(
            (const f32x4*)values, (const i32x4*)argmax, out, flag, IN_F4);
    } else {
        // No workspace: unconditional two-pass path (flag == nullptr).
        zero_fallback<<<2048, block, 0, stream>>>((f32x4*)out, nullptr, OUT_F4);
        scatter_fallback<<<2048, block, 0, stream>>>(
            (const f32x4*)values, (const i32x4*)argmax, out, nullptr, IN_F4);
    }
}